// Round 2
// baseline (266.981 us; speedup 1.0000x reference)
//
#include <hip/hip_runtime.h>
#include <math.h>

#define BLOCK 256
#define CHUNK 2048   // columns per block; multiple of 4*BLOCK, byte offset stays 16B-aligned

__device__ __forceinline__ float waveRedF(float v) {
#pragma unroll
    for (int o = 32; o > 0; o >>= 1) v += __shfl_down(v, o, 64);
    return v;
}
__device__ __forceinline__ unsigned waveRedU(unsigned v) {
#pragma unroll
    for (int o = 32; o > 0; o >>= 1) v += __shfl_down(v, o, 64);
    return v;
}

// truth is exactly 0.0f or 1.0f, so BCE term = -log(t ? p : 1-p), one log per elem.
__device__ __forceinline__ void elem(float p, float t, float& bce,
                                     unsigned& tp, unsigned& tn,
                                     unsigned& gp, unsigned& gn) {
    p = __builtin_isfinite(p) ? p : 0.0f;   // NaN/Inf -> 0 (matches reference)
    const bool tb = t > 0.0f;
    const bool pb = p > 0.5f;
    const float x = tb ? p : (1.0f - p);    // 1-p exact for p in [0.5,1] (Sterbenz)
    bce -= fmaxf(__logf(x), -100.0f);       // log(0) -> -inf -> clamp at -100
    gp += (unsigned)tb;
    gn += (unsigned)(!tb);
    tp += (unsigned)(pb & tb);
    tn += (unsigned)((!pb) & (!tb));
}

// Phase 1: one block per (row, chunk). Writes 5 partials per slot UNCONDITIONALLY
// (slots start as 0xAA poison), so no memset and no atomics are needed.
__global__ __launch_bounds__(BLOCK) void chunkKernel(
    const float* __restrict__ pred, const float* __restrict__ truth,
    const int* __restrict__ lengths, int L, int nchunk, int NB,
    float* __restrict__ bceP, unsigned* __restrict__ cntP) {
    const int row  = blockIdx.x;
    const int c    = blockIdx.y;
    const int slot = row * nchunk + c;
    const int len  = lengths[row];
    const int start = c * CHUNK;
    const int stop  = min(len, start + CHUNK);

    float bce = 0.0f;
    unsigned tp = 0, tn = 0, gp = 0, gn = 0;

    if (start < stop) {
        const float* pr = pred  + (size_t)row * L + start;
        const float* tr = truth + (size_t)row * L + start;
        const int n    = stop - start;          // 1..CHUNK
        const int nvec = n >> 2;
        const float4* pv = (const float4*)pr;
        const float4* tv = (const float4*)tr;
        for (int v = threadIdx.x; v < nvec; v += BLOCK) {
            float4 p4 = pv[v];
            float4 t4 = tv[v];
            elem(p4.x, t4.x, bce, tp, tn, gp, gn);
            elem(p4.y, t4.y, bce, tp, tn, gp, gn);
            elem(p4.z, t4.z, bce, tp, tn, gp, gn);
            elem(p4.w, t4.w, bce, tp, tn, gp, gn);
        }
        const int base = nvec << 2;
        const int tail = n - base;
        if ((int)threadIdx.x < tail) {
            elem(pr[base + threadIdx.x], tr[base + threadIdx.x], bce, tp, tn, gp, gn);
        }
    }

    bce = waveRedF(bce);
    tp = waveRedU(tp); tn = waveRedU(tn);
    gp = waveRedU(gp); gn = waveRedU(gn);

    __shared__ float sf[BLOCK / 64];
    __shared__ unsigned su[4][BLOCK / 64];
    const int wid  = threadIdx.x >> 6;
    const int lane = threadIdx.x & 63;
    if (lane == 0) {
        sf[wid] = bce;
        su[0][wid] = tp; su[1][wid] = tn; su[2][wid] = gp; su[3][wid] = gn;
    }
    __syncthreads();
    if (threadIdx.x == 0) {
        float bsum = 0.0f;
        unsigned ctp = 0, ctn = 0, cgp = 0, cgn = 0;
#pragma unroll
        for (int w = 0; w < BLOCK / 64; w++) {
            bsum += sf[w];
            ctp += su[0][w]; ctn += su[1][w]; cgp += su[2][w]; cgn += su[3][w];
        }
        bceP[slot]          = bsum;
        cntP[slot]          = ctp;
        cntP[NB + slot]     = ctn;
        cntP[2 * NB + slot] = cgp;
        cntP[3 * NB + slot] = cgn;
    }
}

// Phase 2: single block reduces all NB = B*nchunk slots (~320 KB) -> 2 scalars.
__global__ __launch_bounds__(BLOCK) void reduceKernel(
    const float* __restrict__ bceP, const unsigned* __restrict__ cntP,
    const int* __restrict__ lengths, int B, int nchunk, int NB,
    float* __restrict__ out) {
    float loss = 0.0f;
    unsigned tp = 0, tn = 0, gp = 0, gn = 0;

    for (int r = threadIdx.x; r < B; r += BLOCK) {
        float s = 0.0f;
#pragma unroll 4
        for (int c = 0; c < nchunk; c++) s += bceP[r * nchunk + c];
        const int len = lengths[r];
        loss += (len > 0) ? (s / (float)len) : 0.0f;
    }
    for (int i = threadIdx.x; i < NB; i += BLOCK) {
        tp += cntP[i];
        tn += cntP[NB + i];
        gp += cntP[2 * NB + i];
        gn += cntP[3 * NB + i];
    }

    loss = waveRedF(loss);
    tp = waveRedU(tp); tn = waveRedU(tn);
    gp = waveRedU(gp); gn = waveRedU(gn);

    __shared__ float sf[BLOCK / 64];
    __shared__ unsigned su[4][BLOCK / 64];
    const int wid  = threadIdx.x >> 6;
    const int lane = threadIdx.x & 63;
    if (lane == 0) {
        sf[wid] = loss;
        su[0][wid] = tp; su[1][wid] = tn; su[2][wid] = gp; su[3][wid] = gn;
    }
    __syncthreads();
    if (threadIdx.x == 0) {
        float lsum = 0.0f;
        unsigned ctp = 0, ctn = 0, cgp = 0, cgn = 0;
#pragma unroll
        for (int w = 0; w < BLOCK / 64; w++) {
            lsum += sf[w];
            ctp += su[0][w]; ctn += su[1][w]; cgp += su[2][w]; cgn += su[3][w];
        }
        if (cgp == 0) cgp = 1;
        if (cgn == 0) cgn = 1;
        out[0] = lsum / (float)B;
        out[1] = ((float)ctp / (float)cgp) * ((float)ctn / (float)cgn);
    }
}

extern "C" void kernel_launch(void* const* d_in, const int* in_sizes, int n_in,
                              void* d_out, int out_size, void* d_ws, size_t ws_size,
                              hipStream_t stream) {
    const float* pred    = (const float*)d_in[0];
    const float* truth   = (const float*)d_in[1];
    const int*   lengths = (const int*)d_in[2];
    const int B = in_sizes[2];
    const int L = in_sizes[0] / B;
    const int nchunk = (L + CHUNK - 1) / CHUNK;
    const int NB = B * nchunk;

    float*    bceP = (float*)d_ws;
    unsigned* cntP = (unsigned*)((char*)d_ws + (size_t)NB * sizeof(float));

    dim3 grid(B, nchunk);
    chunkKernel<<<grid, BLOCK, 0, stream>>>(pred, truth, lengths, L, nchunk, NB, bceP, cntP);
    reduceKernel<<<1, BLOCK, 0, stream>>>(bceP, cntP, lengths, B, nchunk, NB, (float*)d_out);
}